// Round 1
// baseline (32415.530 us; speedup 1.0000x reference)
//
#include <hip/hip_runtime.h>
#include <stdint.h>

#define S_LEN 1500
#define D_MODEL 1280
#define N_HEAD 20
#define D_HEAD 64
#define FF_DIM 5120
#define N_LAYER 4

// ---------------- helpers ----------------

#if defined(__has_builtin)
#if __has_builtin(__builtin_amdgcn_sdot4)
#define HAVE_SDOT4 1
#endif
#endif

__device__ inline int dot4(int a, int b, int c) {
#ifdef HAVE_SDOT4
    return __builtin_amdgcn_sdot4(a, b, c, false);
#else
    int8_t a0 = (int8_t)(a), a1 = (int8_t)(a >> 8), a2 = (int8_t)(a >> 16), a3 = (int8_t)(a >> 24);
    int8_t b0 = (int8_t)(b), b1 = (int8_t)(b >> 8), b2 = (int8_t)(b >> 16), b3 = (int8_t)(b >> 24);
    return c + (int)a0 * b0 + (int)a1 * b1 + (int)a2 * b2 + (int)a3 * b3;
#endif
}

__device__ inline float gelu_tanh(float x) {
    // jax.nn.gelu default (approximate=True)
    float x3 = x * x * x;
    return 0.5f * x * (1.0f + tanhf(0.7978845608028654f * (x + 0.044715f * x3)));
}

__device__ inline float wred_sum(float v) {
    for (int o = 32; o > 0; o >>= 1) v += __shfl_down(v, o, 64);
    return v;
}
__device__ inline float wred_max(float v) {
    for (int o = 32; o > 0; o >>= 1) v = fmaxf(v, __shfl_down(v, o, 64));
    return v;
}
// blockDim.x == 256 (4 waves) assumed
__device__ inline float block_sum(float v, float* sm4) {
    v = wred_sum(v);
    int w = threadIdx.x >> 6;
    if ((threadIdx.x & 63) == 0) sm4[w] = v;
    __syncthreads();
    float r = sm4[0] + sm4[1] + sm4[2] + sm4[3];
    __syncthreads();
    return r;
}
__device__ inline float block_max(float v, float* sm4) {
    v = wred_max(v);
    int w = threadIdx.x >> 6;
    if ((threadIdx.x & 63) == 0) sm4[w] = v;
    __syncthreads();
    float r = fmaxf(fmaxf(sm4[0], sm4[1]), fmaxf(sm4[2], sm4[3]));
    __syncthreads();
    return r;
}

// ---------------- conv kernels ----------------

__global__ __launch_bounds__(256) void conv1_kernel(
    const float* __restrict__ x,   // [128][3000]
    const float* __restrict__ w,   // [1280][128][3]
    const float* __restrict__ b,   // [1280]
    float* __restrict__ y)         // [1280][3000]
{
    int t = blockIdx.x * 256 + threadIdx.x;
    int o = blockIdx.y;
    if (t >= 3000) return;
    float acc = b[o];
    const float* wr = w + (size_t)o * 384;
    for (int i = 0; i < 128; i++) {
        const float* xr = x + (size_t)i * 3000;
        float x0 = (t >= 1) ? xr[t - 1] : 0.0f;
        float x1 = xr[t];
        float x2 = (t < 2999) ? xr[t + 1] : 0.0f;
        acc += wr[i * 3 + 0] * x0 + wr[i * 3 + 1] * x1 + wr[i * 3 + 2] * x2;
    }
    y[(size_t)o * 3000 + t] = gelu_tanh(acc);
}

__global__ __launch_bounds__(256) void conv2_kernel(
    const float* __restrict__ c1,  // [1280][3000]
    const float* __restrict__ w,   // [1280][1280][3]
    const float* __restrict__ b,   // [1280]
    const float* __restrict__ pos, // [1500][1280]
    float* __restrict__ h)         // [1500][1280]  (transposed + pos added)
{
    int t = blockIdx.x * 256 + threadIdx.x;
    int o = blockIdx.y;
    if (t >= S_LEN) return;
    float acc = b[o];
    const float* wr = w + (size_t)o * 3840;
    int c = 2 * t;  // taps at c-1, c, c+1 ; c+1 <= 2999 always
    for (int i = 0; i < 1280; i++) {
        const float* xr = c1 + (size_t)i * 3000;
        float x0 = (c >= 1) ? xr[c - 1] : 0.0f;
        float x1 = xr[c];
        float x2 = xr[c + 1];
        acc += wr[i * 3 + 0] * x0 + wr[i * 3 + 1] * x1 + wr[i * 3 + 2] * x2;
    }
    h[(size_t)t * D_MODEL + o] = gelu_tanh(acc) + pos[(size_t)t * D_MODEL + o];
}

// ---------------- quantization kernels ----------------

// per-row weight quant: block per row
__global__ __launch_bounds__(256) void wquant_kernel(
    const float* __restrict__ w, int8_t* __restrict__ qw,
    float* __restrict__ ws, int K)
{
    int r = blockIdx.x;
    int tid = threadIdx.x;
    __shared__ float sm4[4];
    const float* wr = w + (size_t)r * K;
    float mx = 0.0f;
    for (int i = tid; i < K; i += 256) mx = fmaxf(mx, fabsf(wr[i]));
    mx = block_max(mx, sm4);
    float sc = fmaxf(mx / 127.0f, 1e-8f);
    if (tid == 0) ws[r] = sc;
    for (int i = tid; i < K; i += 256) {
        float qv = rintf(wr[i] / sc);
        qv = fminf(fmaxf(qv, -128.0f), 127.0f);
        qw[(size_t)r * K + i] = (int8_t)qv;
    }
}

// RMSNorm + per-token quant, D=1280, block per token
__global__ __launch_bounds__(256) void rmsnorm_quant_kernel(
    const float* __restrict__ x, const float* __restrict__ w,
    const float* __restrict__ b, int8_t* __restrict__ q,
    float* __restrict__ sx)
{
    int s = blockIdx.x;
    int tid = threadIdx.x;
    __shared__ float sm4[4];
    const float* xr = x + (size_t)s * D_MODEL;
    float v[5];
    float ss = 0.0f;
    for (int i = 0; i < 5; i++) {
        float t = xr[tid + 256 * i];
        v[i] = t;
        ss += t * t;
    }
    ss = block_sum(ss, sm4);
    float inv = rsqrtf(ss * (1.0f / 1280.0f) + 1e-6f);
    float mx = 0.0f;
    for (int i = 0; i < 5; i++) {
        int idx = tid + 256 * i;
        float t = v[i] * inv * w[idx] + b[idx];
        v[i] = t;
        mx = fmaxf(mx, fabsf(t));
    }
    mx = block_max(mx, sm4);
    float sc = fmaxf(mx / 127.0f, 1e-8f);
    if (tid == 0) sx[s] = sc;
    for (int i = 0; i < 5; i++) {
        float qv = rintf(v[i] / sc);
        qv = fminf(fmaxf(qv, -128.0f), 127.0f);
        q[(size_t)s * D_MODEL + tid + 256 * i] = (int8_t)qv;
    }
}

// per-token quant (optionally with fused gelu), arbitrary D; block per token
template <bool GELU>
__global__ __launch_bounds__(256) void quant_kernel(
    const float* __restrict__ x, int8_t* __restrict__ q,
    float* __restrict__ sx, int Dm)
{
    int s = blockIdx.x;
    int tid = threadIdx.x;
    __shared__ float sm4[4];
    const float* xr = x + (size_t)s * Dm;
    float mx = 0.0f;
    for (int i = tid; i < Dm; i += 256) {
        float t = xr[i];
        if (GELU) t = gelu_tanh(t);
        mx = fmaxf(mx, fabsf(t));
    }
    mx = block_max(mx, sm4);
    float sc = fmaxf(mx / 127.0f, 1e-8f);
    if (tid == 0) sx[s] = sc;
    for (int i = tid; i < Dm; i += 256) {
        float t = xr[i];
        if (GELU) t = gelu_tanh(t);
        float qv = rintf(t / sc);
        qv = fminf(fmaxf(qv, -128.0f), 127.0f);
        q[(size_t)s * Dm + i] = (int8_t)qv;
    }
}

// ---------------- int8 GEMM ----------------
// out[s,o] = (sum_k qx[s,k]*qw[o,k]) * sx[s] * ws[o] + bias[o] (+ res[s,o])
__global__ __launch_bounds__(256) void gemm_w8a8(
    const int8_t* __restrict__ qx, const float* __restrict__ sx,
    const int8_t* __restrict__ qw, const float* __restrict__ ws,
    const float* __restrict__ bias, const float* __restrict__ res,
    float* __restrict__ out, int Srows, int O, int K)
{
    int o = blockIdx.x * 16 + (threadIdx.x & 15);
    int s = blockIdx.y * 16 + (threadIdx.x >> 4);
    if (s >= Srows) return;
    const int4* xr = (const int4*)(qx + (size_t)s * K);
    const int4* wr = (const int4*)(qw + (size_t)o * K);
    int acc = 0;
    int n16 = K >> 4;
    for (int i = 0; i < n16; i++) {
        int4 a = xr[i];
        int4 bb = wr[i];
        acc = dot4(a.x, bb.x, acc);
        acc = dot4(a.y, bb.y, acc);
        acc = dot4(a.z, bb.z, acc);
        acc = dot4(a.w, bb.w, acc);
    }
    float y = (float)acc * sx[s] * ws[o] + bias[o];
    if (res) y += res[(size_t)s * O + o];
    out[(size_t)s * O + o] = y;
}

// ---------------- attention ----------------
// block per (q, head); qkv layout [S][3840] with q|k|v each [H][64]
__global__ __launch_bounds__(256) void attn_kernel(
    const float* __restrict__ qkv, float* __restrict__ ao)
{
    __shared__ float qv[64];
    __shared__ float p[S_LEN];
    __shared__ float sm4[4];
    __shared__ float partial[4][64];
    int qi = blockIdx.x, h = blockIdx.y, tid = threadIdx.x;
    if (tid < 64) qv[tid] = qkv[(size_t)qi * 3840 + h * 64 + tid];
    __syncthreads();
    float lmax = -INFINITY;
    for (int k = tid; k < S_LEN; k += 256) {
        const float* kr = qkv + (size_t)k * 3840 + 1280 + h * 64;
        float d = 0.0f;
        for (int j = 0; j < 64; j++) d += qv[j] * kr[j];
        d *= 0.125f;  // DH^-0.5
        p[k] = d;
        lmax = fmaxf(lmax, d);
    }
    float gmax = block_max(lmax, sm4);
    float lsum = 0.0f;
    for (int k = tid; k < S_LEN; k += 256) {
        float e = expf(p[k] - gmax);
        p[k] = e;
        lsum += e;
    }
    float gsum = block_sum(lsum, sm4);  // internal barrier orders p writes
    float rinv = 1.0f / gsum;
    int g = tid >> 6, d = tid & 63;
    float acc = 0.0f;
    for (int k = g; k < S_LEN; k += 4) {
        acc += p[k] * qkv[(size_t)k * 3840 + 2560 + h * 64 + d];
    }
    partial[g][d] = acc;
    __syncthreads();
    if (tid < 64) {
        float t = partial[0][tid] + partial[1][tid] + partial[2][tid] + partial[3][tid];
        ao[(size_t)qi * D_MODEL + h * 64 + tid] = t * rinv;
    }
}

// ---------------- final pool + layernorm ----------------
__global__ __launch_bounds__(256) void pool_ln_kernel(
    const float* __restrict__ h, const float* __restrict__ w,
    const float* __restrict__ b, float* __restrict__ out)
{
    int t = blockIdx.x;
    int tid = threadIdx.x;
    __shared__ float sm4[4];
    const float* r0 = h + (size_t)(2 * t) * D_MODEL;
    const float* r1 = r0 + D_MODEL;
    float v[5];
    float s1 = 0.0f;
    for (int i = 0; i < 5; i++) {
        int idx = tid + 256 * i;
        float x = 0.5f * (r0[idx] + r1[idx]);
        v[i] = x;
        s1 += x;
    }
    float mu = block_sum(s1, sm4) * (1.0f / 1280.0f);
    float s2 = 0.0f;
    for (int i = 0; i < 5; i++) {
        float d = v[i] - mu;
        s2 += d * d;
    }
    float var = block_sum(s2, sm4) * (1.0f / 1280.0f);
    float inv = rsqrtf(var + 1e-5f);
    for (int i = 0; i < 5; i++) {
        int idx = tid + 256 * i;
        out[(size_t)t * D_MODEL + idx] = (v[i] - mu) * inv * w[idx] + b[idx];
    }
}

// ---------------- host ----------------

static inline size_t al256(size_t x) { return (x + 255) & ~(size_t)255; }

extern "C" void kernel_launch(void* const* d_in, const int* in_sizes, int n_in,
                              void* d_out, int out_size, void* d_ws, size_t ws_size,
                              hipStream_t stream) {
    const float* in_feat = (const float*)d_in[0];   // [1][128][3000]
    const float* conv1_w = (const float*)d_in[1];
    const float* conv1_b = (const float*)d_in[2];
    const float* conv2_w = (const float*)d_in[3];
    const float* conv2_b = (const float*)d_in[4];
    const float* pos_emb = (const float*)d_in[5];
    const float* ln1_w   = (const float*)d_in[6];
    const float* ln1_b   = (const float*)d_in[7];
    const float* qkv_w   = (const float*)d_in[8];
    const float* qkv_b   = (const float*)d_in[9];
    const float* out_w   = (const float*)d_in[10];
    const float* out_b   = (const float*)d_in[11];
    const float* ln2_w   = (const float*)d_in[12];
    const float* ln2_b   = (const float*)d_in[13];
    const float* fc1_w   = (const float*)d_in[14];
    const float* fc1_b   = (const float*)d_in[15];
    const float* fc2_w   = (const float*)d_in[16];
    const float* fc2_b   = (const float*)d_in[17];
    const float* lnf_w   = (const float*)d_in[18];
    const float* lnf_b   = (const float*)d_in[19];
    float* outp = (float*)d_out;

    char* ws = (char*)d_ws;
    size_t off = 0;
    auto carve = [&](size_t bytes) {
        void* p = ws + off;
        off += al256(bytes);
        return p;
    };
    float*  c1      = (float*)carve((size_t)1280 * 3000 * 4);
    float*  hA      = (float*)carve((size_t)S_LEN * D_MODEL * 4);
    float*  hB      = (float*)carve((size_t)S_LEN * D_MODEL * 4);
    float*  qkvbuf  = (float*)carve((size_t)S_LEN * 3840 * 4);
    float*  aobuf   = (float*)carve((size_t)S_LEN * D_MODEL * 4);
    float*  f1buf   = (float*)carve((size_t)S_LEN * FF_DIM * 4);
    int8_t* q8      = (int8_t*)carve((size_t)S_LEN * FF_DIM);
    float*  sx      = (float*)carve((size_t)S_LEN * 4);
    int8_t* qw_qkv  = (int8_t*)carve((size_t)3840 * 1280);
    float*  ws_qkv  = (float*)carve((size_t)3840 * 4);
    int8_t* qw_out  = (int8_t*)carve((size_t)1280 * 1280);
    float*  ws_out  = (float*)carve((size_t)1280 * 4);
    int8_t* qw_fc1  = (int8_t*)carve((size_t)5120 * 1280);
    float*  ws_fc1  = (float*)carve((size_t)5120 * 4);
    int8_t* qw_fc2  = (int8_t*)carve((size_t)1280 * 5120);
    float*  ws_fc2  = (float*)carve((size_t)1280 * 4);
    (void)ws_size; (void)n_in; (void)in_sizes; (void)out_size;

    // conv stem
    conv1_kernel<<<dim3(12, 1280), 256, 0, stream>>>(in_feat, conv1_w, conv1_b, c1);
    conv2_kernel<<<dim3(6, 1280), 256, 0, stream>>>(c1, conv2_w, conv2_b, pos_emb, hA);

    float* h = hA;
    float* hn = hB;
    const int sgrid = (S_LEN + 15) / 16;  // 94

    for (int l = 0; l < N_LAYER; l++) {
        // quantize this layer's weights
        wquant_kernel<<<3840, 256, 0, stream>>>(qkv_w + (size_t)l * 3840 * 1280, qw_qkv, ws_qkv, 1280);
        wquant_kernel<<<1280, 256, 0, stream>>>(out_w + (size_t)l * 1280 * 1280, qw_out, ws_out, 1280);
        wquant_kernel<<<5120, 256, 0, stream>>>(fc1_w + (size_t)l * 5120 * 1280, qw_fc1, ws_fc1, 1280);
        wquant_kernel<<<1280, 256, 0, stream>>>(fc2_w + (size_t)l * 1280 * 5120, qw_fc2, ws_fc2, 5120);

        // attention block
        rmsnorm_quant_kernel<<<S_LEN, 256, 0, stream>>>(h, ln1_w + l * D_MODEL, ln1_b + l * D_MODEL, q8, sx);
        gemm_w8a8<<<dim3(3840 / 16, sgrid), 256, 0, stream>>>(q8, sx, qw_qkv, ws_qkv,
            qkv_b + (size_t)l * 3840, nullptr, qkvbuf, S_LEN, 3840, 1280);
        attn_kernel<<<dim3(S_LEN, N_HEAD), 256, 0, stream>>>(qkvbuf, aobuf);
        quant_kernel<false><<<S_LEN, 256, 0, stream>>>(aobuf, q8, sx, D_MODEL);
        gemm_w8a8<<<dim3(1280 / 16, sgrid), 256, 0, stream>>>(q8, sx, qw_out, ws_out,
            out_b + (size_t)l * 1280, h, hn, S_LEN, 1280, 1280);
        { float* t = h; h = hn; hn = t; }

        // MLP block
        rmsnorm_quant_kernel<<<S_LEN, 256, 0, stream>>>(h, ln2_w + l * D_MODEL, ln2_b + l * D_MODEL, q8, sx);
        gemm_w8a8<<<dim3(5120 / 16, sgrid), 256, 0, stream>>>(q8, sx, qw_fc1, ws_fc1,
            fc1_b + (size_t)l * 5120, nullptr, f1buf, S_LEN, 5120, 1280);
        quant_kernel<true><<<S_LEN, 256, 0, stream>>>(f1buf, q8, sx, FF_DIM);
        gemm_w8a8<<<dim3(1280 / 16, sgrid), 256, 0, stream>>>(q8, sx, qw_fc2, ws_fc2,
            fc2_b + (size_t)l * 1280, h, hn, S_LEN, 1280, 5120);
        { float* t = h; h = hn; hn = t; }
    }

    pool_ln_kernel<<<750, 256, 0, stream>>>(h, lnf_w, lnf_b, outp);
}

// Round 2
// 11473.407 us; speedup vs baseline: 2.8253x; 2.8253x over previous
//
#include <hip/hip_runtime.h>
#include <stdint.h>

#define S_LEN 1500
#define D_MODEL 1280
#define N_HEAD 20
#define D_HEAD 64
#define FF_DIM 5120
#define N_LAYER 4

typedef int v4i __attribute__((ext_vector_type(4)));

// ---------------- helpers ----------------

__device__ inline float gelu_tanh(float x) {
    // jax.nn.gelu default (approximate=True)
    float x3 = x * x * x;
    return 0.5f * x * (1.0f + tanhf(0.7978845608028654f * (x + 0.044715f * x3)));
}

__device__ inline float wred_sum(float v) {
    for (int o = 32; o > 0; o >>= 1) v += __shfl_down(v, o, 64);
    return v;
}
__device__ inline float wred_max(float v) {
    for (int o = 32; o > 0; o >>= 1) v = fmaxf(v, __shfl_down(v, o, 64));
    return v;
}
// blockDim.x == 256 (4 waves) assumed
__device__ inline float block_sum(float v, float* sm4) {
    v = wred_sum(v);
    int w = threadIdx.x >> 6;
    if ((threadIdx.x & 63) == 0) sm4[w] = v;
    __syncthreads();
    float r = sm4[0] + sm4[1] + sm4[2] + sm4[3];
    __syncthreads();
    return r;
}
__device__ inline float block_max(float v, float* sm4) {
    v = wred_max(v);
    int w = threadIdx.x >> 6;
    if ((threadIdx.x & 63) == 0) sm4[w] = v;
    __syncthreads();
    float r = fmaxf(fmaxf(sm4[0], sm4[1]), fmaxf(sm4[2], sm4[3]));
    __syncthreads();
    return r;
}

// ---------------- conv stem: im2col + f32 GEMM ----------------

// A1[t][tap*128+i] = in[i][t-1+tap], t in [0,3000)
__global__ __launch_bounds__(256) void im2col1_kernel(
    const float* __restrict__ x, float* __restrict__ A1)
{
    int t = blockIdx.x * 256 + threadIdx.x;
    int col = blockIdx.y;  // 0..383
    if (t >= 3000) return;
    int tap = col >> 7, i = col & 127;
    int src = t - 1 + tap;
    float v = (src >= 0 && src < 3000) ? x[(size_t)i * 3000 + src] : 0.0f;
    A1[(size_t)t * 384 + col] = v;
}

// A2[t][tap*1280+o] = g1[2t-1+tap][o], t in [0,1500)
__global__ __launch_bounds__(256) void im2col2_kernel(
    const float* __restrict__ g1, float* __restrict__ A2)
{
    int col = blockIdx.x * 256 + threadIdx.x;  // 0..3839
    int t = blockIdx.y;
    if (col >= 3840) return;
    int tap = col / 1280, o = col - tap * 1280;
    int src = 2 * t - 1 + tap;
    float v = (src >= 0 && src < 3000) ? g1[(size_t)src * 1280 + o] : 0.0f;
    A2[(size_t)t * 3840 + col] = v;
}

// out[o][tap*C+i] = w[o][i][tap]
__global__ __launch_bounds__(256) void wreorder_kernel(
    const float* __restrict__ w, float* __restrict__ wo, int C)
{
    int o = blockIdx.x;
    int KC = 3 * C;
    const float* wr = w + (size_t)o * KC;
    float* orow = wo + (size_t)o * KC;
    for (int col = threadIdx.x; col < KC; col += 256) {
        int tap = col / C, i = col - tap * C;
        orow[col] = wr[i * 3 + tap];
    }
}

// C[m][n] = gelu(A[m,:]*W[n,:] + bias[n]) (+ pos[m][n] if EPI==1)
// 64x64 tile, BK=16, 256 threads, 4x4 per thread
template <int EPI>
__global__ __launch_bounds__(256) void gemm_f32_kernel(
    const float* __restrict__ A, const float* __restrict__ W,
    const float* __restrict__ bias, const float* __restrict__ pos,
    float* __restrict__ out, int M, int N, int K)
{
    __shared__ float As[16][68];
    __shared__ float Bs[16][68];
    int tid = threadIdx.x;
    int tx = tid & 15, ty = tid >> 4;
    int m0 = blockIdx.y * 64, n0 = blockIdx.x * 64;
    int lr = tid >> 2;        // 0..63 tile row
    int lk = (tid & 3) * 4;   // k sub-offset
    int am = m0 + lr; if (am >= M) am = M - 1;
    const float* Ap = A + (size_t)am * K + lk;
    const float* Wp = W + (size_t)(n0 + lr) * K + lk;
    float c[4][4] = {};
    for (int k0 = 0; k0 < K; k0 += 16) {
        float4 av = *(const float4*)(Ap + k0);
        float4 wv = *(const float4*)(Wp + k0);
        __syncthreads();
        As[lk + 0][lr] = av.x; As[lk + 1][lr] = av.y; As[lk + 2][lr] = av.z; As[lk + 3][lr] = av.w;
        Bs[lk + 0][lr] = wv.x; Bs[lk + 1][lr] = wv.y; Bs[lk + 2][lr] = wv.z; Bs[lk + 3][lr] = wv.w;
        __syncthreads();
        #pragma unroll
        for (int kk = 0; kk < 16; kk++) {
            float4 a4 = *(const float4*)&As[kk][ty * 4];
            float4 b4 = *(const float4*)&Bs[kk][tx * 4];
            float ar[4] = {a4.x, a4.y, a4.z, a4.w};
            float br[4] = {b4.x, b4.y, b4.z, b4.w};
            #pragma unroll
            for (int i = 0; i < 4; i++)
                #pragma unroll
                for (int j = 0; j < 4; j++)
                    c[i][j] += ar[i] * br[j];
        }
    }
    #pragma unroll
    for (int i = 0; i < 4; i++) {
        int m = m0 + ty * 4 + i;
        if (m >= M) continue;
        #pragma unroll
        for (int j = 0; j < 4; j++) {
            int n = n0 + tx * 4 + j;
            float v = gelu_tanh(c[i][j] + bias[n]);
            if (EPI == 1) v += pos[(size_t)m * N + n];
            out[(size_t)m * N + n] = v;
        }
    }
}

// ---------------- quantization kernels ----------------

// per-row weight quant: block per row, float4
__global__ __launch_bounds__(256) void wquant_kernel(
    const float* __restrict__ w, int8_t* __restrict__ qw,
    float* __restrict__ ws, int K)
{
    int r = blockIdx.x;
    int tid = threadIdx.x;
    __shared__ float sm4[4];
    const float4* wr = (const float4*)(w + (size_t)r * K);
    int n4 = K >> 2;
    float mx = 0.0f;
    for (int i = tid; i < n4; i += 256) {
        float4 v = wr[i];
        mx = fmaxf(mx, fmaxf(fmaxf(fabsf(v.x), fabsf(v.y)), fmaxf(fabsf(v.z), fabsf(v.w))));
    }
    mx = block_max(mx, sm4);
    float sc = fmaxf(mx / 127.0f, 1e-8f);
    if (tid == 0) ws[r] = sc;
    float rs = 1.0f / sc;
    char4* qr = (char4*)(qw + (size_t)r * K);
    for (int i = tid; i < n4; i += 256) {
        float4 v = wr[i];
        char4 q;
        q.x = (int8_t)fminf(fmaxf(rintf(v.x * rs), -128.0f), 127.0f);
        q.y = (int8_t)fminf(fmaxf(rintf(v.y * rs), -128.0f), 127.0f);
        q.z = (int8_t)fminf(fmaxf(rintf(v.z * rs), -128.0f), 127.0f);
        q.w = (int8_t)fminf(fmaxf(rintf(v.w * rs), -128.0f), 127.0f);
        qr[i] = q;
    }
}

// RMSNorm + per-token quant, D=1280, block per token
__global__ __launch_bounds__(256) void rmsnorm_quant_kernel(
    const float* __restrict__ x, const float* __restrict__ w,
    const float* __restrict__ b, int8_t* __restrict__ q,
    float* __restrict__ sx)
{
    int s = blockIdx.x;
    int tid = threadIdx.x;
    __shared__ float sm4[4];
    const float* xr = x + (size_t)s * D_MODEL;
    float v[5];
    float ss = 0.0f;
    for (int i = 0; i < 5; i++) {
        float t = xr[tid + 256 * i];
        v[i] = t;
        ss += t * t;
    }
    ss = block_sum(ss, sm4);
    float inv = rsqrtf(ss * (1.0f / 1280.0f) + 1e-6f);
    float mx = 0.0f;
    for (int i = 0; i < 5; i++) {
        int idx = tid + 256 * i;
        float t = v[i] * inv * w[idx] + b[idx];
        v[i] = t;
        mx = fmaxf(mx, fabsf(t));
    }
    mx = block_max(mx, sm4);
    float sc = fmaxf(mx / 127.0f, 1e-8f);
    if (tid == 0) sx[s] = sc;
    float rs = 1.0f / sc;
    for (int i = 0; i < 5; i++) {
        float qv = rintf(v[i] * rs);
        qv = fminf(fmaxf(qv, -128.0f), 127.0f);
        q[(size_t)s * D_MODEL + tid + 256 * i] = (int8_t)qv;
    }
}

// per-token quant (optionally fused gelu); block per token
template <bool GELU>
__global__ __launch_bounds__(256) void quant_kernel(
    const float* __restrict__ x, int8_t* __restrict__ q,
    float* __restrict__ sx, int Dm)
{
    int s = blockIdx.x;
    int tid = threadIdx.x;
    __shared__ float sm4[4];
    const float4* xr = (const float4*)(x + (size_t)s * Dm);
    int n4 = Dm >> 2;
    float mx = 0.0f;
    for (int i = tid; i < n4; i += 256) {
        float4 t = xr[i];
        if (GELU) { t.x = gelu_tanh(t.x); t.y = gelu_tanh(t.y); t.z = gelu_tanh(t.z); t.w = gelu_tanh(t.w); }
        mx = fmaxf(mx, fmaxf(fmaxf(fabsf(t.x), fabsf(t.y)), fmaxf(fabsf(t.z), fabsf(t.w))));
    }
    mx = block_max(mx, sm4);
    float sc = fmaxf(mx / 127.0f, 1e-8f);
    if (tid == 0) sx[s] = sc;
    float rs = 1.0f / sc;
    char4* qr = (char4*)(q + (size_t)s * Dm);
    for (int i = tid; i < n4; i += 256) {
        float4 t = xr[i];
        if (GELU) { t.x = gelu_tanh(t.x); t.y = gelu_tanh(t.y); t.z = gelu_tanh(t.z); t.w = gelu_tanh(t.w); }
        char4 qq;
        qq.x = (int8_t)fminf(fmaxf(rintf(t.x * rs), -128.0f), 127.0f);
        qq.y = (int8_t)fminf(fmaxf(rintf(t.y * rs), -128.0f), 127.0f);
        qq.z = (int8_t)fminf(fmaxf(rintf(t.z * rs), -128.0f), 127.0f);
        qq.w = (int8_t)fminf(fmaxf(rintf(t.w * rs), -128.0f), 127.0f);
        qr[i] = qq;
    }
}

// ---------------- int8 GEMM via MFMA ----------------
// out[m,n] = (sum_k qx[m,k]*qw[n,k]) * sx[m] * ws[n] + bias[n] (+ res[m,n])
// block: 4 waves; wave w computes rows [by*64+w*16, +16) x cols [bx*64, +64)
__global__ __launch_bounds__(256) void gemm_w8a8_mfma(
    const int8_t* __restrict__ qx, const float* __restrict__ sx,
    const int8_t* __restrict__ qw, const float* __restrict__ ws,
    const float* __restrict__ bias, const float* __restrict__ res,
    float* __restrict__ out, int M, int O, int K)
{
    int lane = threadIdx.x & 63;
    int wv = threadIdx.x >> 6;
    int l15 = lane & 15;
    int quad = lane >> 4;
    int m_base = blockIdx.y * 64 + wv * 16;
    int n_base = blockIdx.x * 64;

    int ar = m_base + l15; if (ar >= M) ar = M - 1;
    const int8_t* ap = qx + (size_t)ar * K + quad * 16;
    const int8_t* bp = qw + (size_t)(n_base + l15) * K + quad * 16;
    size_t rowK16 = (size_t)16 * K;

    v4i acc0 = {0, 0, 0, 0}, acc1 = {0, 0, 0, 0}, acc2 = {0, 0, 0, 0}, acc3 = {0, 0, 0, 0};
    int nsteps = K >> 6;
    for (int s = 0; s < nsteps; s++) {
        v4i a  = *(const v4i*)(ap + s * 64);
        v4i b0 = *(const v4i*)(bp + s * 64);
        v4i b1 = *(const v4i*)(bp + rowK16 + s * 64);
        v4i b2 = *(const v4i*)(bp + 2 * rowK16 + s * 64);
        v4i b3 = *(const v4i*)(bp + 3 * rowK16 + s * 64);
        acc0 = __builtin_amdgcn_mfma_i32_16x16x64_i8(a, b0, acc0, 0, 0, 0);
        acc1 = __builtin_amdgcn_mfma_i32_16x16x64_i8(a, b1, acc1, 0, 0, 0);
        acc2 = __builtin_amdgcn_mfma_i32_16x16x64_i8(a, b2, acc2, 0, 0, 0);
        acc3 = __builtin_amdgcn_mfma_i32_16x16x64_i8(a, b3, acc3, 0, 0, 0);
    }

    // D layout: row m = m_base + quad*4 + r, col n = n_base + nb*16 + l15
    float sxv[4];
    #pragma unroll
    for (int r = 0; r < 4; r++) {
        int m = m_base + quad * 4 + r;
        sxv[r] = (m < M) ? sx[m] : 0.0f;
    }
    v4i accs[4] = {acc0, acc1, acc2, acc3};
    #pragma unroll
    for (int nb = 0; nb < 4; nb++) {
        int n = n_base + nb * 16 + l15;
        float wn = ws[n];
        float bn = bias[n];
        #pragma unroll
        for (int r = 0; r < 4; r++) {
            int m = m_base + quad * 4 + r;
            if (m < M) {
                float y = (float)accs[nb][r] * sxv[r] * wn + bn;
                if (res) y += res[(size_t)m * O + n];
                out[(size_t)m * O + n] = y;
            }
        }
    }
}

// ---------------- attention ----------------
// block per (q, head); qkv layout [S][3840] with q|k|v each [H][64]
__global__ __launch_bounds__(256) void attn_kernel(
    const float* __restrict__ qkv, float* __restrict__ ao)
{
    __shared__ float4 qv4[16];
    __shared__ float p[S_LEN];
    __shared__ float sm4[4];
    __shared__ float partial[4][64];
    int qi = blockIdx.x, h = blockIdx.y, tid = threadIdx.x;
    if (tid < 16) qv4[tid] = ((const float4*)(qkv + (size_t)qi * 3840 + h * 64))[tid];
    __syncthreads();
    float lmax = -INFINITY;
    for (int k = tid; k < S_LEN; k += 256) {
        const float4* kr = (const float4*)(qkv + (size_t)k * 3840 + 1280 + h * 64);
        float d = 0.0f;
        #pragma unroll
        for (int j = 0; j < 16; j++) {
            float4 kk = kr[j];
            float4 qq = qv4[j];
            d += qq.x * kk.x + qq.y * kk.y + qq.z * kk.z + qq.w * kk.w;
        }
        d *= 0.125f;  // DH^-0.5
        p[k] = d;
        lmax = fmaxf(lmax, d);
    }
    float gmax = block_max(lmax, sm4);
    float lsum = 0.0f;
    for (int k = tid; k < S_LEN; k += 256) {
        float e = expf(p[k] - gmax);
        p[k] = e;
        lsum += e;
    }
    float gsum = block_sum(lsum, sm4);  // internal barrier orders p writes
    float rinv = 1.0f / gsum;
    int g = tid >> 6, d = tid & 63;
    float acc = 0.0f;
    for (int k = g; k < S_LEN; k += 4) {
        acc += p[k] * qkv[(size_t)k * 3840 + 2560 + h * 64 + d];
    }
    partial[g][d] = acc;
    __syncthreads();
    if (tid < 64) {
        float t = partial[0][tid] + partial[1][tid] + partial[2][tid] + partial[3][tid];
        ao[(size_t)qi * D_MODEL + h * 64 + tid] = t * rinv;
    }
}

// ---------------- final pool + layernorm ----------------
__global__ __launch_bounds__(256) void pool_ln_kernel(
    const float* __restrict__ h, const float* __restrict__ w,
    const float* __restrict__ b, float* __restrict__ out)
{
    int t = blockIdx.x;
    int tid = threadIdx.x;
    __shared__ float sm4[4];
    const float* r0 = h + (size_t)(2 * t) * D_MODEL;
    const float* r1 = r0 + D_MODEL;
    float v[5];
    float s1 = 0.0f;
    for (int i = 0; i < 5; i++) {
        int idx = tid + 256 * i;
        float x = 0.5f * (r0[idx] + r1[idx]);
        v[i] = x;
        s1 += x;
    }
    float mu = block_sum(s1, sm4) * (1.0f / 1280.0f);
    float s2 = 0.0f;
    for (int i = 0; i < 5; i++) {
        float d = v[i] - mu;
        s2 += d * d;
    }
    float var = block_sum(s2, sm4) * (1.0f / 1280.0f);
    float inv = rsqrtf(var + 1e-5f);
    for (int i = 0; i < 5; i++) {
        int idx = tid + 256 * i;
        out[(size_t)t * D_MODEL + idx] = (v[i] - mu) * inv * w[idx] + b[idx];
    }
}

// ---------------- host ----------------

static inline size_t al256(size_t x) { return (x + 255) & ~(size_t)255; }

extern "C" void kernel_launch(void* const* d_in, const int* in_sizes, int n_in,
                              void* d_out, int out_size, void* d_ws, size_t ws_size,
                              hipStream_t stream) {
    const float* in_feat = (const float*)d_in[0];   // [1][128][3000]
    const float* conv1_w = (const float*)d_in[1];
    const float* conv1_b = (const float*)d_in[2];
    const float* conv2_w = (const float*)d_in[3];
    const float* conv2_b = (const float*)d_in[4];
    const float* pos_emb = (const float*)d_in[5];
    const float* ln1_w   = (const float*)d_in[6];
    const float* ln1_b   = (const float*)d_in[7];
    const float* qkv_w   = (const float*)d_in[8];
    const float* qkv_b   = (const float*)d_in[9];
    const float* out_w   = (const float*)d_in[10];
    const float* out_b   = (const float*)d_in[11];
    const float* ln2_w   = (const float*)d_in[12];
    const float* ln2_b   = (const float*)d_in[13];
    const float* fc1_w   = (const float*)d_in[14];
    const float* fc1_b   = (const float*)d_in[15];
    const float* fc2_w   = (const float*)d_in[16];
    const float* fc2_b   = (const float*)d_in[17];
    const float* lnf_w   = (const float*)d_in[18];
    const float* lnf_b   = (const float*)d_in[19];
    float* outp = (float*)d_out;

    char* ws = (char*)d_ws;
    size_t off = 0;
    auto carve = [&](size_t bytes) {
        void* p = ws + off;
        off += al256(bytes);
        return p;
    };
    float*  hA      = (float*)carve((size_t)S_LEN * D_MODEL * 4);
    float*  hB      = (float*)carve((size_t)S_LEN * D_MODEL * 4);
    float*  qkvbuf  = (float*)carve((size_t)S_LEN * 3840 * 4);       // also g1 / W2r
    float*  aobuf   = (float*)carve((size_t)S_LEN * D_MODEL * 4);    // also W1r
    float*  f1buf   = (float*)carve((size_t)S_LEN * FF_DIM * 4);     // also A2
    int8_t* q8      = (int8_t*)carve((size_t)S_LEN * FF_DIM);        // also A1
    float*  sx      = (float*)carve((size_t)S_LEN * 4);
    int8_t* qw_qkv  = (int8_t*)carve((size_t)3840 * 1280);
    float*  ws_qkv  = (float*)carve((size_t)3840 * 4);
    int8_t* qw_out  = (int8_t*)carve((size_t)1280 * 1280);
    float*  ws_out  = (float*)carve((size_t)1280 * 4);
    int8_t* qw_fc1  = (int8_t*)carve((size_t)5120 * 1280);
    float*  ws_fc1  = (float*)carve((size_t)5120 * 4);
    int8_t* qw_fc2  = (int8_t*)carve((size_t)1280 * 5120);
    float*  ws_fc2  = (float*)carve((size_t)1280 * 4);
    (void)ws_size; (void)n_in; (void)in_sizes; (void)out_size;

    // conv stem aliases (all consumed before the transformer loop starts)
    float* A1  = (float*)q8;      // 3000*384*4  = 4.6 MB  <= 7.68 MB
    float* W1r = aobuf;           // 1280*384*4  = 2.0 MB  <= 7.68 MB
    float* g1  = qkvbuf;          // 3000*1280*4 = 15.4 MB <= 23 MB
    float* A2  = f1buf;           // 1500*3840*4 = 23 MB   <= 30.7 MB
    float* W2r = qkvbuf;          // 1280*3840*4 = 19.7 MB <= 23 MB (after g1 consumed)

    // conv1: im2col (K=384) + f32 GEMM + gelu -> g1[3000][1280]
    im2col1_kernel<<<dim3(12, 384), 256, 0, stream>>>(in_feat, A1);
    wreorder_kernel<<<1280, 256, 0, stream>>>(conv1_w, W1r, 128);
    gemm_f32_kernel<0><<<dim3(20, 47), 256, 0, stream>>>(A1, W1r, conv1_b, nullptr, g1, 3000, 1280, 384);
    // conv2: im2col (row concat, K=3840) + f32 GEMM + gelu + pos -> hA[1500][1280]
    im2col2_kernel<<<dim3(15, 1500), 256, 0, stream>>>(g1, A2);
    wreorder_kernel<<<1280, 256, 0, stream>>>(conv2_w, W2r, 1280);
    gemm_f32_kernel<1><<<dim3(20, 24), 256, 0, stream>>>(A2, W2r, conv2_b, pos_emb, hA, 1500, 1280, 3840);

    float* h = hA;
    float* hn = hB;
    const int mtiles = (S_LEN + 63) / 64;  // 24

    for (int l = 0; l < N_LAYER; l++) {
        // quantize this layer's weights
        wquant_kernel<<<3840, 256, 0, stream>>>(qkv_w + (size_t)l * 3840 * 1280, qw_qkv, ws_qkv, 1280);
        wquant_kernel<<<1280, 256, 0, stream>>>(out_w + (size_t)l * 1280 * 1280, qw_out, ws_out, 1280);
        wquant_kernel<<<5120, 256, 0, stream>>>(fc1_w + (size_t)l * 5120 * 1280, qw_fc1, ws_fc1, 1280);
        wquant_kernel<<<1280, 256, 0, stream>>>(fc2_w + (size_t)l * 1280 * 5120, qw_fc2, ws_fc2, 5120);

        // attention block
        rmsnorm_quant_kernel<<<S_LEN, 256, 0, stream>>>(h, ln1_w + l * D_MODEL, ln1_b + l * D_MODEL, q8, sx);
        gemm_w8a8_mfma<<<dim3(60, mtiles), 256, 0, stream>>>(q8, sx, qw_qkv, ws_qkv,
            qkv_b + (size_t)l * 3840, nullptr, qkvbuf, S_LEN, 3840, 1280);
        attn_kernel<<<dim3(S_LEN, N_HEAD), 256, 0, stream>>>(qkvbuf, aobuf);
        quant_kernel<false><<<S_LEN, 256, 0, stream>>>(aobuf, q8, sx, D_MODEL);
        gemm_w8a8_mfma<<<dim3(20, mtiles), 256, 0, stream>>>(q8, sx, qw_out, ws_out,
            out_b + (size_t)l * 1280, h, hn, S_LEN, 1280, 1280);
        { float* t = h; h = hn; hn = t; }

        // MLP block
        rmsnorm_quant_kernel<<<S_LEN, 256, 0, stream>>>(h, ln2_w + l * D_MODEL, ln2_b + l * D_MODEL, q8, sx);
        gemm_w8a8_mfma<<<dim3(80, mtiles), 256, 0, stream>>>(q8, sx, qw_fc1, ws_fc1,
            fc1_b + (size_t)l * 5120, nullptr, f1buf, S_LEN, 5120, 1280);
        quant_kernel<true><<<S_LEN, 256, 0, stream>>>(f1buf, q8, sx, FF_DIM);
        gemm_w8a8_mfma<<<dim3(20, mtiles), 256, 0, stream>>>(q8, sx, qw_fc2, ws_fc2,
            fc2_b + (size_t)l * 1280, h, hn, S_LEN, 1280, 5120);
        { float* t = h; h = hn; hn = t; }
    }

    pool_ln_kernel<<<750, 256, 0, stream>>>(h, lnf_w, lnf_b, outp);
}

// Round 3
// 2755.456 us; speedup vs baseline: 11.7641x; 4.1639x over previous
//
#include <hip/hip_runtime.h>
#include <stdint.h>

#define S_LEN 1500
#define D_MODEL 1280
#define N_HEAD 20
#define D_HEAD 64
#define FF_DIM 5120
#define N_LAYER 4

typedef int v4i __attribute__((ext_vector_type(4)));

// ---------------- helpers ----------------

__device__ inline float gelu_tanh(float x) {
    // jax.nn.gelu default (approximate=True)
    float x3 = x * x * x;
    return 0.5f * x * (1.0f + tanhf(0.7978845608028654f * (x + 0.044715f * x3)));
}

__device__ inline float wred_sum(float v) {
    for (int o = 32; o > 0; o >>= 1) v += __shfl_down(v, o, 64);
    return v;
}
__device__ inline float wred_max(float v) {
    for (int o = 32; o > 0; o >>= 1) v = fmaxf(v, __shfl_down(v, o, 64));
    return v;
}
// blockDim.x == 256 (4 waves) assumed
__device__ inline float block_sum(float v, float* sm4) {
    v = wred_sum(v);
    int w = threadIdx.x >> 6;
    if ((threadIdx.x & 63) == 0) sm4[w] = v;
    __syncthreads();
    float r = sm4[0] + sm4[1] + sm4[2] + sm4[3];
    __syncthreads();
    return r;
}
__device__ inline float block_max(float v, float* sm4) {
    v = wred_max(v);
    int w = threadIdx.x >> 6;
    if ((threadIdx.x & 63) == 0) sm4[w] = v;
    __syncthreads();
    float r = fmaxf(fmaxf(sm4[0], sm4[1]), fmaxf(sm4[2], sm4[3]));
    __syncthreads();
    return r;
}

// ---------------- conv stem: im2col + f32 GEMM ----------------

// A1[t][tap*128+i] = in[i][t-1+tap], t in [0,3000)
__global__ __launch_bounds__(256) void im2col1_kernel(
    const float* __restrict__ x, float* __restrict__ A1)
{
    int t = blockIdx.x * 256 + threadIdx.x;
    int col = blockIdx.y;  // 0..383
    if (t >= 3000) return;
    int tap = col >> 7, i = col & 127;
    int src = t - 1 + tap;
    float v = (src >= 0 && src < 3000) ? x[(size_t)i * 3000 + src] : 0.0f;
    A1[(size_t)t * 384 + col] = v;
}

// A2[t][tap*1280+o] = g1[2t-1+tap][o], t in [0,1500)
__global__ __launch_bounds__(256) void im2col2_kernel(
    const float* __restrict__ g1, float* __restrict__ A2)
{
    int col = blockIdx.x * 256 + threadIdx.x;  // 0..3839
    int t = blockIdx.y;
    if (col >= 3840) return;
    int tap = col / 1280, o = col - tap * 1280;
    int src = 2 * t - 1 + tap;
    float v = (src >= 0 && src < 3000) ? g1[(size_t)src * 1280 + o] : 0.0f;
    A2[(size_t)t * 3840 + col] = v;
}

// out[o][tap*C+i] = w[o][i][tap]
__global__ __launch_bounds__(256) void wreorder_kernel(
    const float* __restrict__ w, float* __restrict__ wo, int C)
{
    int o = blockIdx.x;
    int KC = 3 * C;
    const float* wr = w + (size_t)o * KC;
    float* orow = wo + (size_t)o * KC;
    for (int col = threadIdx.x; col < KC; col += 256) {
        int tap = col / C, i = col - tap * C;
        orow[col] = wr[i * 3 + tap];
    }
}

// C[m][n] = gelu(A[m,:]*W[n,:] + bias[n]) (+ pos[m][n] if EPI==1)
// 64x64 tile, BK=16, 256 threads, 4x4 per thread
template <int EPI>
__global__ __launch_bounds__(256) void gemm_f32_kernel(
    const float* __restrict__ A, const float* __restrict__ W,
    const float* __restrict__ bias, const float* __restrict__ pos,
    float* __restrict__ out, int M, int N, int K)
{
    __shared__ float As[16][68];
    __shared__ float Bs[16][68];
    int tid = threadIdx.x;
    int tx = tid & 15, ty = tid >> 4;
    int m0 = blockIdx.y * 64, n0 = blockIdx.x * 64;
    int lr = tid >> 2;        // 0..63 tile row
    int lk = (tid & 3) * 4;   // k sub-offset
    int am = m0 + lr; if (am >= M) am = M - 1;
    const float* Ap = A + (size_t)am * K + lk;
    const float* Wp = W + (size_t)(n0 + lr) * K + lk;
    float c[4][4] = {};
    for (int k0 = 0; k0 < K; k0 += 16) {
        float4 av = *(const float4*)(Ap + k0);
        float4 wv = *(const float4*)(Wp + k0);
        __syncthreads();
        As[lk + 0][lr] = av.x; As[lk + 1][lr] = av.y; As[lk + 2][lr] = av.z; As[lk + 3][lr] = av.w;
        Bs[lk + 0][lr] = wv.x; Bs[lk + 1][lr] = wv.y; Bs[lk + 2][lr] = wv.z; Bs[lk + 3][lr] = wv.w;
        __syncthreads();
        #pragma unroll
        for (int kk = 0; kk < 16; kk++) {
            float4 a4 = *(const float4*)&As[kk][ty * 4];
            float4 b4 = *(const float4*)&Bs[kk][tx * 4];
            float ar[4] = {a4.x, a4.y, a4.z, a4.w};
            float br[4] = {b4.x, b4.y, b4.z, b4.w};
            #pragma unroll
            for (int i = 0; i < 4; i++)
                #pragma unroll
                for (int j = 0; j < 4; j++)
                    c[i][j] += ar[i] * br[j];
        }
    }
    #pragma unroll
    for (int i = 0; i < 4; i++) {
        int m = m0 + ty * 4 + i;
        if (m >= M) continue;
        #pragma unroll
        for (int j = 0; j < 4; j++) {
            int n = n0 + tx * 4 + j;
            float v = gelu_tanh(c[i][j] + bias[n]);
            if (EPI == 1) v += pos[(size_t)m * N + n];
            out[(size_t)m * N + n] = v;
        }
    }
}

// ---------------- quantization kernels ----------------

// per-row weight quant: block per row, float4
__global__ __launch_bounds__(256) void wquant_kernel(
    const float* __restrict__ w, int8_t* __restrict__ qw,
    float* __restrict__ ws, int K)
{
    int r = blockIdx.x;
    int tid = threadIdx.x;
    __shared__ float sm4[4];
    const float4* wr = (const float4*)(w + (size_t)r * K);
    int n4 = K >> 2;
    float mx = 0.0f;
    for (int i = tid; i < n4; i += 256) {
        float4 v = wr[i];
        mx = fmaxf(mx, fmaxf(fmaxf(fabsf(v.x), fabsf(v.y)), fmaxf(fabsf(v.z), fabsf(v.w))));
    }
    mx = block_max(mx, sm4);
    float sc = fmaxf(mx / 127.0f, 1e-8f);
    if (tid == 0) ws[r] = sc;
    float rs = 1.0f / sc;
    char4* qr = (char4*)(qw + (size_t)r * K);
    for (int i = tid; i < n4; i += 256) {
        float4 v = wr[i];
        char4 q;
        q.x = (int8_t)fminf(fmaxf(rintf(v.x * rs), -128.0f), 127.0f);
        q.y = (int8_t)fminf(fmaxf(rintf(v.y * rs), -128.0f), 127.0f);
        q.z = (int8_t)fminf(fmaxf(rintf(v.z * rs), -128.0f), 127.0f);
        q.w = (int8_t)fminf(fmaxf(rintf(v.w * rs), -128.0f), 127.0f);
        qr[i] = q;
    }
}

// RMSNorm + per-token quant, D=1280, block per token
__global__ __launch_bounds__(256) void rmsnorm_quant_kernel(
    const float* __restrict__ x, const float* __restrict__ w,
    const float* __restrict__ b, int8_t* __restrict__ q,
    float* __restrict__ sx)
{
    int s = blockIdx.x;
    int tid = threadIdx.x;
    __shared__ float sm4[4];
    const float* xr = x + (size_t)s * D_MODEL;
    float v[5];
    float ss = 0.0f;
    for (int i = 0; i < 5; i++) {
        float t = xr[tid + 256 * i];
        v[i] = t;
        ss += t * t;
    }
    ss = block_sum(ss, sm4);
    float inv = rsqrtf(ss * (1.0f / 1280.0f) + 1e-6f);
    float mx = 0.0f;
    for (int i = 0; i < 5; i++) {
        int idx = tid + 256 * i;
        float t = v[i] * inv * w[idx] + b[idx];
        v[i] = t;
        mx = fmaxf(mx, fabsf(t));
    }
    mx = block_max(mx, sm4);
    float sc = fmaxf(mx / 127.0f, 1e-8f);
    if (tid == 0) sx[s] = sc;
    float rs = 1.0f / sc;
    for (int i = 0; i < 5; i++) {
        float qv = rintf(v[i] * rs);
        qv = fminf(fmaxf(qv, -128.0f), 127.0f);
        q[(size_t)s * D_MODEL + tid + 256 * i] = (int8_t)qv;
    }
}

// per-token quant (optionally fused gelu); block per token
template <bool GELU>
__global__ __launch_bounds__(256) void quant_kernel(
    const float* __restrict__ x, int8_t* __restrict__ q,
    float* __restrict__ sx, int Dm)
{
    int s = blockIdx.x;
    int tid = threadIdx.x;
    __shared__ float sm4[4];
    const float4* xr = (const float4*)(x + (size_t)s * Dm);
    int n4 = Dm >> 2;
    float mx = 0.0f;
    for (int i = tid; i < n4; i += 256) {
        float4 t = xr[i];
        if (GELU) { t.x = gelu_tanh(t.x); t.y = gelu_tanh(t.y); t.z = gelu_tanh(t.z); t.w = gelu_tanh(t.w); }
        mx = fmaxf(mx, fmaxf(fmaxf(fabsf(t.x), fabsf(t.y)), fmaxf(fabsf(t.z), fabsf(t.w))));
    }
    mx = block_max(mx, sm4);
    float sc = fmaxf(mx / 127.0f, 1e-8f);
    if (tid == 0) sx[s] = sc;
    float rs = 1.0f / sc;
    char4* qr = (char4*)(q + (size_t)s * Dm);
    for (int i = tid; i < n4; i += 256) {
        float4 t = xr[i];
        if (GELU) { t.x = gelu_tanh(t.x); t.y = gelu_tanh(t.y); t.z = gelu_tanh(t.z); t.w = gelu_tanh(t.w); }
        char4 qq;
        qq.x = (int8_t)fminf(fmaxf(rintf(t.x * rs), -128.0f), 127.0f);
        qq.y = (int8_t)fminf(fmaxf(rintf(t.y * rs), -128.0f), 127.0f);
        qq.z = (int8_t)fminf(fmaxf(rintf(t.z * rs), -128.0f), 127.0f);
        qq.w = (int8_t)fminf(fmaxf(rintf(t.w * rs), -128.0f), 127.0f);
        qr[i] = qq;
    }
}

// ---------------- int8 GEMM via MFMA ----------------
// out[m,n] = (sum_k qx[m,k]*qw[n,k]) * sx[m] * ws[n] + bias[n] (+ res[m,n])
__global__ __launch_bounds__(256) void gemm_w8a8_mfma(
    const int8_t* __restrict__ qx, const float* __restrict__ sx,
    const int8_t* __restrict__ qw, const float* __restrict__ ws,
    const float* __restrict__ bias, const float* __restrict__ res,
    float* __restrict__ out, int M, int O, int K)
{
    int lane = threadIdx.x & 63;
    int wv = threadIdx.x >> 6;
    int l15 = lane & 15;
    int quad = lane >> 4;
    int m_base = blockIdx.y * 64 + wv * 16;
    int n_base = blockIdx.x * 64;

    int ar = m_base + l15; if (ar >= M) ar = M - 1;
    const int8_t* ap = qx + (size_t)ar * K + quad * 16;
    const int8_t* bp = qw + (size_t)(n_base + l15) * K + quad * 16;
    size_t rowK16 = (size_t)16 * K;

    v4i acc0 = {0, 0, 0, 0}, acc1 = {0, 0, 0, 0}, acc2 = {0, 0, 0, 0}, acc3 = {0, 0, 0, 0};
    int nsteps = K >> 6;
    for (int s = 0; s < nsteps; s++) {
        v4i a  = *(const v4i*)(ap + s * 64);
        v4i b0 = *(const v4i*)(bp + s * 64);
        v4i b1 = *(const v4i*)(bp + rowK16 + s * 64);
        v4i b2 = *(const v4i*)(bp + 2 * rowK16 + s * 64);
        v4i b3 = *(const v4i*)(bp + 3 * rowK16 + s * 64);
        acc0 = __builtin_amdgcn_mfma_i32_16x16x64_i8(a, b0, acc0, 0, 0, 0);
        acc1 = __builtin_amdgcn_mfma_i32_16x16x64_i8(a, b1, acc1, 0, 0, 0);
        acc2 = __builtin_amdgcn_mfma_i32_16x16x64_i8(a, b2, acc2, 0, 0, 0);
        acc3 = __builtin_amdgcn_mfma_i32_16x16x64_i8(a, b3, acc3, 0, 0, 0);
    }

    float sxv[4];
    #pragma unroll
    for (int r = 0; r < 4; r++) {
        int m = m_base + quad * 4 + r;
        sxv[r] = (m < M) ? sx[m] : 0.0f;
    }
    v4i accs[4] = {acc0, acc1, acc2, acc3};
    #pragma unroll
    for (int nb = 0; nb < 4; nb++) {
        int n = n_base + nb * 16 + l15;
        float wn = ws[n];
        float bn = bias[n];
        #pragma unroll
        for (int r = 0; r < 4; r++) {
            int m = m_base + quad * 4 + r;
            if (m < M) {
                float y = (float)accs[nb][r] * sxv[r] * wn + bn;
                if (res) y += res[(size_t)m * O + n];
                out[(size_t)m * O + n] = y;
            }
        }
    }
}

// ---------------- attention: tiled flash-style, f32 ----------------
// grid (24 q-tiles, 20 heads), 256 threads.
// Thread (tx=tid&15, ty=tid>>4): queries q0=4*ty.., keys/dims 4*tx..
// qkv layout [S][3840] with q|k|v each [H][64]
__global__ __launch_bounds__(256) void attn_tiled_kernel(
    const float* __restrict__ qkv, float* __restrict__ ao)
{
    __shared__ float Qs[64][68];
    __shared__ float KV[64][68];   // K-tile as [d][k], then V-tile as [k][d]
    __shared__ float Ps[64][68];
    int h = blockIdx.y;
    int q_tile = blockIdx.x;
    int tid = threadIdx.x;
    int tx = tid & 15, ty = tid >> 4;
    int q0 = ty * 4;   // tile-local query base
    int d0 = tx * 4;   // dim base (for PV/output)

    // load Q tile: 64 rows x 64 dims (rows clamped; OOB rows never stored)
    {
        int r = tid >> 2;
        int dq = (tid & 3) * 16;
        int qg = q_tile * 64 + r;
        int qc = qg < S_LEN ? qg : S_LEN - 1;
        const float4* src = (const float4*)(qkv + (size_t)qc * 3840 + h * 64 + dq);
        #pragma unroll
        for (int i = 0; i < 4; i++)
            *(float4*)&Qs[r][dq + i * 4] = src[i];
    }

    float O[4][4] = {};
    float m_run[4], l_run[4];
    #pragma unroll
    for (int i = 0; i < 4; i++) { m_run[i] = -INFINITY; l_run[i] = 0.0f; }

    for (int kt = 0; kt < 24; kt++) {
        int kbase = kt * 64;
        int krem = S_LEN - kbase;  // valid keys in this tile (>=28)

        __syncthreads();  // prev PV done reading KV/Ps (also covers Q-load on kt==0)
        // load K tile transposed: KV[d][k]
        {
            int kk = tid >> 2;
            int dq = (tid & 3) * 16;
            int kg = kbase + kk;
            int kc = kg < S_LEN ? kg : S_LEN - 1;
            const float4* src = (const float4*)(qkv + (size_t)kc * 3840 + 1280 + h * 64 + dq);
            #pragma unroll
            for (int i = 0; i < 4; i++) {
                float4 v = src[i];
                KV[dq + i * 4 + 0][kk] = v.x;
                KV[dq + i * 4 + 1][kk] = v.y;
                KV[dq + i * 4 + 2][kk] = v.z;
                KV[dq + i * 4 + 3][kk] = v.w;
            }
        }
        __syncthreads();

        // scores: s[i][j] = Q[q0+i] . K[k0loc+j]
        float s[4][4] = {};
        int k0loc = tx * 4;
        for (int d = 0; d < 64; d += 4) {
            float4 qv[4], kv[4];
            #pragma unroll
            for (int i = 0; i < 4; i++) qv[i] = *(const float4*)&Qs[q0 + i][d];
            #pragma unroll
            for (int dd = 0; dd < 4; dd++) kv[dd] = *(const float4*)&KV[d + dd][k0loc];
            #pragma unroll
            for (int i = 0; i < 4; i++) {
                float qa[4] = {qv[i].x, qv[i].y, qv[i].z, qv[i].w};
                #pragma unroll
                for (int dd = 0; dd < 4; dd++) {
                    float kb[4] = {kv[dd].x, kv[dd].y, kv[dd].z, kv[dd].w};
                    #pragma unroll
                    for (int j = 0; j < 4; j++)
                        s[i][j] += qa[dd] * kb[j];
                }
            }
        }
        // oops: fix index pairing (qa must be indexed by dd) -- done via qa[4] per i below
        // (note: loop above multiplies qa[dd]*kb[j]; qa[] holds q over dd. correct.)

        // scale + mask
        #pragma unroll
        for (int i = 0; i < 4; i++)
            #pragma unroll
            for (int j = 0; j < 4; j++) {
                s[i][j] *= 0.125f;
                if (k0loc + j >= krem) s[i][j] = -INFINITY;
            }

        // online softmax per query row (butterfly over the 16 tx lanes)
        #pragma unroll
        for (int i = 0; i < 4; i++) {
            float t = fmaxf(fmaxf(s[i][0], s[i][1]), fmaxf(s[i][2], s[i][3]));
            #pragma unroll
            for (int msk = 1; msk < 16; msk <<= 1)
                t = fmaxf(t, __shfl_xor(t, msk, 64));
            float mn = fmaxf(m_run[i], t);
            float alpha = __expf(m_run[i] - mn);
            m_run[i] = mn;
            float rs = 0.0f;
            #pragma unroll
            for (int j = 0; j < 4; j++) {
                float p = __expf(s[i][j] - mn);
                s[i][j] = p;
                rs += p;
            }
            #pragma unroll
            for (int msk = 1; msk < 16; msk <<= 1)
                rs += __shfl_xor(rs, msk, 64);
            l_run[i] = l_run[i] * alpha + rs;
            #pragma unroll
            for (int j = 0; j < 4; j++) O[i][j] *= alpha;
            *(float4*)&Ps[q0 + i][k0loc] = *(float4*)&s[i][0];
        }
        __syncthreads();  // S-stage reads of KV done; Ps visible

        // load V tile: KV[k][d]
        {
            int kk = tid >> 2;
            int dq = (tid & 3) * 16;
            int kg = kbase + kk;
            int kc = kg < S_LEN ? kg : S_LEN - 1;
            const float4* src = (const float4*)(qkv + (size_t)kc * 3840 + 2560 + h * 64 + dq);
            #pragma unroll
            for (int i = 0; i < 4; i++)
                *(float4*)&KV[kk][dq + i * 4] = src[i];
        }
        __syncthreads();

        // PV: O[i][j] += sum_k Ps[q0+i][k] * V[k][d0+j]
        for (int kb = 0; kb < 64; kb += 4) {
            float4 pv[4], vv[4];
            #pragma unroll
            for (int i = 0; i < 4; i++) pv[i] = *(const float4*)&Ps[q0 + i][kb];
            #pragma unroll
            for (int kk = 0; kk < 4; kk++) vv[kk] = *(const float4*)&KV[kb + kk][d0];
            #pragma unroll
            for (int i = 0; i < 4; i++) {
                float pa[4] = {pv[i].x, pv[i].y, pv[i].z, pv[i].w};
                #pragma unroll
                for (int kk = 0; kk < 4; kk++) {
                    float vb[4] = {vv[kk].x, vv[kk].y, vv[kk].z, vv[kk].w};
                    #pragma unroll
                    for (int j = 0; j < 4; j++)
                        O[i][j] += pa[kk] * vb[j];
                }
            }
        }
    }

    // epilogue
    #pragma unroll
    for (int i = 0; i < 4; i++) {
        int qg = q_tile * 64 + q0 + i;
        if (qg < S_LEN) {
            float rl = 1.0f / l_run[i];
            float4 o;
            o.x = O[i][0] * rl; o.y = O[i][1] * rl; o.z = O[i][2] * rl; o.w = O[i][3] * rl;
            *(float4*)(ao + (size_t)qg * D_MODEL + h * 64 + d0) = o;
        }
    }
}

// ---------------- final pool + layernorm ----------------
__global__ __launch_bounds__(256) void pool_ln_kernel(
    const float* __restrict__ h, const float* __restrict__ w,
    const float* __restrict__ b, float* __restrict__ out)
{
    int t = blockIdx.x;
    int tid = threadIdx.x;
    __shared__ float sm4[4];
    const float* r0 = h + (size_t)(2 * t) * D_MODEL;
    const float* r1 = r0 + D_MODEL;
    float v[5];
    float s1 = 0.0f;
    for (int i = 0; i < 5; i++) {
        int idx = tid + 256 * i;
        float x = 0.5f * (r0[idx] + r1[idx]);
        v[i] = x;
        s1 += x;
    }
    float mu = block_sum(s1, sm4) * (1.0f / 1280.0f);
    float s2 = 0.0f;
    for (int i = 0; i < 5; i++) {
        float d = v[i] - mu;
        s2 += d * d;
    }
    float var = block_sum(s2, sm4) * (1.0f / 1280.0f);
    float inv = rsqrtf(var + 1e-5f);
    for (int i = 0; i < 5; i++) {
        int idx = tid + 256 * i;
        out[(size_t)t * D_MODEL + idx] = (v[i] - mu) * inv * w[idx] + b[idx];
    }
}

// ---------------- host ----------------

static inline size_t al256(size_t x) { return (x + 255) & ~(size_t)255; }

extern "C" void kernel_launch(void* const* d_in, const int* in_sizes, int n_in,
                              void* d_out, int out_size, void* d_ws, size_t ws_size,
                              hipStream_t stream) {
    const float* in_feat = (const float*)d_in[0];   // [1][128][3000]
    const float* conv1_w = (const float*)d_in[1];
    const float* conv1_b = (const float*)d_in[2];
    const float* conv2_w = (const float*)d_in[3];
    const float* conv2_b = (const float*)d_in[4];
    const float* pos_emb = (const float*)d_in[5];
    const float* ln1_w   = (const float*)d_in[6];
    const float* ln1_b   = (const float*)d_in[7];
    const float* qkv_w   = (const float*)d_in[8];
    const float* qkv_b   = (const float*)d_in[9];
    const float* out_w   = (const float*)d_in[10];
    const float* out_b   = (const float*)d_in[11];
    const float* ln2_w   = (const float*)d_in[12];
    const float* ln2_b   = (const float*)d_in[13];
    const float* fc1_w   = (const float*)d_in[14];
    const float* fc1_b   = (const float*)d_in[15];
    const float* fc2_w   = (const float*)d_in[16];
    const float* fc2_b   = (const float*)d_in[17];
    const float* lnf_w   = (const float*)d_in[18];
    const float* lnf_b   = (const float*)d_in[19];
    float* outp = (float*)d_out;

    char* ws = (char*)d_ws;
    size_t off = 0;
    auto carve = [&](size_t bytes) {
        void* p = ws + off;
        off += al256(bytes);
        return p;
    };
    float*  hA      = (float*)carve((size_t)S_LEN * D_MODEL * 4);
    float*  hB      = (float*)carve((size_t)S_LEN * D_MODEL * 4);
    float*  qkvbuf  = (float*)carve((size_t)S_LEN * 3840 * 4);       // also g1 / W2r
    float*  aobuf   = (float*)carve((size_t)S_LEN * D_MODEL * 4);    // also W1r
    float*  f1buf   = (float*)carve((size_t)S_LEN * FF_DIM * 4);     // also A2
    int8_t* q8      = (int8_t*)carve((size_t)S_LEN * FF_DIM);        // also A1
    float*  sx      = (float*)carve((size_t)S_LEN * 4);
    int8_t* qw_qkv  = (int8_t*)carve((size_t)3840 * 1280);
    float*  ws_qkv  = (float*)carve((size_t)3840 * 4);
    int8_t* qw_out  = (int8_t*)carve((size_t)1280 * 1280);
    float*  ws_out  = (float*)carve((size_t)1280 * 4);
    int8_t* qw_fc1  = (int8_t*)carve((size_t)5120 * 1280);
    float*  ws_fc1  = (float*)carve((size_t)5120 * 4);
    int8_t* qw_fc2  = (int8_t*)carve((size_t)1280 * 5120);
    float*  ws_fc2  = (float*)carve((size_t)1280 * 4);
    (void)ws_size; (void)n_in; (void)in_sizes; (void)out_size;

    // conv stem aliases (all consumed before the transformer loop starts)
    float* A1  = (float*)q8;      // 3000*384*4  = 4.6 MB  <= 7.68 MB
    float* W1r = aobuf;           // 1280*384*4  = 2.0 MB  <= 7.68 MB
    float* g1  = qkvbuf;          // 3000*1280*4 = 15.4 MB <= 23 MB
    float* A2  = f1buf;           // 1500*3840*4 = 23 MB   <= 30.7 MB
    float* W2r = qkvbuf;          // 1280*3840*4 = 19.7 MB <= 23 MB (after g1 consumed)

    // conv1: im2col (K=384) + f32 GEMM + gelu -> g1[3000][1280]
    im2col1_kernel<<<dim3(12, 384), 256, 0, stream>>>(in_feat, A1);
    wreorder_kernel<<<1280, 256, 0, stream>>>(conv1_w, W1r, 128);
    gemm_f32_kernel<0><<<dim3(20, 47), 256, 0, stream>>>(A1, W1r, conv1_b, nullptr, g1, 3000, 1280, 384);
    // conv2: im2col (row concat, K=3840) + f32 GEMM + gelu + pos -> hA[1500][1280]
    im2col2_kernel<<<dim3(15, 1500), 256, 0, stream>>>(g1, A2);
    wreorder_kernel<<<1280, 256, 0, stream>>>(conv2_w, W2r, 1280);
    gemm_f32_kernel<1><<<dim3(20, 24), 256, 0, stream>>>(A2, W2r, conv2_b, pos_emb, hA, 1500, 1280, 3840);

    float* h = hA;
    float* hn = hB;
    const int mtiles = (S_LEN + 63) / 64;  // 24

    for (int l = 0; l < N_LAYER; l++) {
        // quantize this layer's weights
        wquant_kernel<<<3840, 256, 0, stream>>>(qkv_w + (size_t)l * 3840 * 1280, qw_qkv, ws_qkv, 1280);
        wquant_kernel<<<1280, 256, 0, stream>>>(out_w + (size_t)l * 1280 * 1280, qw_out, ws_out, 1280);
        wquant_kernel<<<5120, 256, 0, stream>>>(fc1_w + (size_t)l * 5120 * 1280, qw_fc1, ws_fc1, 1280);
        wquant_kernel<<<1280, 256, 0, stream>>>(fc2_w + (size_t)l * 1280 * 5120, qw_fc2, ws_fc2, 5120);

        // attention block
        rmsnorm_quant_kernel<<<S_LEN, 256, 0, stream>>>(h, ln1_w + l * D_MODEL, ln1_b + l * D_MODEL, q8, sx);
        gemm_w8a8_mfma<<<dim3(60, mtiles), 256, 0, stream>>>(q8, sx, qw_qkv, ws_qkv,
            qkv_b + (size_t)l * 3840, nullptr, qkvbuf, S_LEN, 3840, 1280);
        attn_tiled_kernel<<<dim3(24, N_HEAD), 256, 0, stream>>>(qkvbuf, aobuf);
        quant_kernel<false><<<S_LEN, 256, 0, stream>>>(aobuf, q8, sx, D_MODEL);
        gemm_w8a8_mfma<<<dim3(20, mtiles), 256, 0, stream>>>(q8, sx, qw_out, ws_out,
            out_b + (size_t)l * 1280, h, hn, S_LEN, 1280, 1280);
        { float* t = h; h = hn; hn = t; }

        // MLP block
        rmsnorm_quant_kernel<<<S_LEN, 256, 0, stream>>>(h, ln2_w + l * D_MODEL, ln2_b + l * D_MODEL, q8, sx);
        gemm_w8a8_mfma<<<dim3(80, mtiles), 256, 0, stream>>>(q8, sx, qw_fc1, ws_fc1,
            fc1_b + (size_t)l * 5120, nullptr, f1buf, S_LEN, 5120, 1280);
        quant_kernel<true><<<S_LEN, 256, 0, stream>>>(f1buf, q8, sx, FF_DIM);
        gemm_w8a8_mfma<<<dim3(20, mtiles), 256, 0, stream>>>(q8, sx, qw_fc2, ws_fc2,
            fc2_b + (size_t)l * 1280, h, hn, S_LEN, 1280, 5120);
        { float* t = h; h = hn; hn = t; }
    }

    pool_ln_kernel<<<750, 256, 0, stream>>>(h, lnf_w, lnf_b, outp);
}